// Round 8
// baseline (175.972 us; speedup 1.0000x reference)
//
#include <hip/hip_runtime.h>
#include <math.h>

#define T_DIM 2048
#define B_DIM 2
#define E_DIM 1024
#define K_DIM 64
#define H_DIM 16
#define R_DIM (T_DIM * B_DIM)   // 4096 rows, row r = t*B + b
#define WROWS 2176              // Wq(1024) + Wv(1024) + Wk(64) + pad(64)
#define NCH 16                  // T chunks of 128 (linear-attention state)

typedef __bf16 bf16x8 __attribute__((ext_vector_type(8)));
typedef __bf16 bf16x4 __attribute__((ext_vector_type(4)));
typedef float f32x4 __attribute__((ext_vector_type(4)));

#define GLD16(gptr, lptr)                                                      \
    __builtin_amdgcn_global_load_lds(                                          \
        (const __attribute__((address_space(1))) void*)(gptr),                 \
        (__attribute__((address_space(3))) void*)(lptr), 16, 0, 0)

// ---------------------------------------------------------------------------
// Fused fp32->bf16 conversion: blocks [0,2048) convert x (4M elems);
// blocks [2048,3136) convert W-concat [Wq;Wv;Wk;pad] (2176*1024 elems).
// ---------------------------------------------------------------------------
__global__ __launch_bounds__(256) void cvt_all(const float* __restrict__ X,
                                               const float* __restrict__ Wq,
                                               const float* __restrict__ Wv,
                                               const float* __restrict__ Wk,
                                               __bf16* __restrict__ XB,
                                               __bf16* __restrict__ WB) {
    const size_t nq = (size_t)1024 * 1024;
    const size_t nk = (size_t)64 * 1024;
    bf16x8 o;
    if (blockIdx.x < 2048) {
        size_t g = ((size_t)blockIdx.x * 256 + threadIdx.x) * 8;
        float4 a = *(const float4*)&X[g];
        float4 b = *(const float4*)&X[g + 4];
        o[0] = (__bf16)a.x; o[1] = (__bf16)a.y; o[2] = (__bf16)a.z; o[3] = (__bf16)a.w;
        o[4] = (__bf16)b.x; o[5] = (__bf16)b.y; o[6] = (__bf16)b.z; o[7] = (__bf16)b.w;
        *(bf16x8*)&XB[g] = o;
    } else {
        size_t g = ((size_t)(blockIdx.x - 2048) * 256 + threadIdx.x) * 8;
        if (g < 2 * nq + nk) {
            const float* src;
            size_t off;
            if (g < nq)          { src = Wq; off = g; }
            else if (g < 2 * nq) { src = Wv; off = g - nq; }
            else                 { src = Wk; off = g - 2 * nq; }
            float4 a = *(const float4*)&src[off];
            float4 b = *(const float4*)&src[off + 4];
            o[0] = (__bf16)a.x; o[1] = (__bf16)a.y; o[2] = (__bf16)a.z; o[3] = (__bf16)a.w;
            o[4] = (__bf16)b.x; o[5] = (__bf16)b.y; o[6] = (__bf16)b.z; o[7] = (__bf16)b.w;
        } else {
#pragma unroll
            for (int i = 0; i < 8; ++i) o[i] = (__bf16)0.f;
        }
        *(bf16x8*)&WB[g] = o;
    }
}

// ---------------------------------------------------------------------------
// bf16 MFMA GEMM round-16: r7 core + counted-vmcnt software pipeline.
// r4 counters: latency-bound (MfmaUtil 13%, all pipes idle, 2.1 blocks/CU).
// __syncthreads' implicit vmcnt(0) serially exposed every gld_lds. Now:
// double-buffered LDS, STAGE(next) issued BEFORE compute, RAW s_barrier +
// explicit `s_waitcnt vmcnt(4)` -- waits only for current tile's 4 loads,
// next tile's 4 stay in flight under 16 MFMA + 8 ds_read (~400cy covers
// L2-hit ~200-300cy). m139/HK pattern; counted-N is exact (gld_lds are the
// only vmcnt ops in the loop). Regime-gated: m139 was null at 4 blocks/CU
// (TLP-rich); here 2.1/CU TLP-poor -> overlap has room to act (rule #23).
// ---------------------------------------------------------------------------
__global__ __launch_bounds__(256) void gemm_mfma(const __bf16* __restrict__ XB,
                                                 const __bf16* __restrict__ WB,
                                                 const float* __restrict__ bq,
                                                 const float* __restrict__ bv,
                                                 const float* __restrict__ bk,
                                                 __bf16* __restrict__ Qb,
                                                 __bf16* __restrict__ Vb,
                                                 float* __restrict__ Kr) {
    __shared__ __bf16 Als[2][128 * 32];   // 16 KB
    __shared__ __bf16 Bls[2][128 * 32];   // 16 KB
    const int bid = blockIdx.x;                 // 0..543
    const int v = (bid & 7) * 68 + (bid >> 3);  // bijective XCD chunking (r7)
    const int bx = v / 17;                      // row-tile 0..31
    const int by = v % 17;                      // col-tile 0..16
    const int tid = threadIdx.x;
    const int lane = tid & 63;
    const int w = tid >> 6;
    const int wm = (w & 1) * 64;
    const int wn = (w >> 1) * 64;
    const int rBase = bx * 128;
    const int cBase = by * 128;

    const int c0 = tid, c1 = tid + 256;
    const __bf16* gA0 = XB + (size_t)(rBase + (c0 >> 2)) * E_DIM + (c0 & 3) * 8;
    const __bf16* gA1 = XB + (size_t)(rBase + (c1 >> 2)) * E_DIM + (c1 & 3) * 8;
    const __bf16* gB0 = WB + (size_t)(cBase + (c0 >> 2)) * E_DIM + (c0 & 3) * 8;
    const __bf16* gB1 = WB + (size_t)(cBase + (c1 >> 2)) * E_DIM + (c1 & 3) * 8;

    const int fr = lane & 15;
    const int fk = (lane >> 4) * 8;

    f32x4 acc[4][4] = {};

#define STAGE(B, KK)                                                           \
    {                                                                          \
        GLD16(gA0 + (KK), &Als[B][c0 * 8]);                                    \
        GLD16(gA1 + (KK), &Als[B][c1 * 8]);                                    \
        GLD16(gB0 + (KK), &Bls[B][c0 * 8]);                                    \
        GLD16(gB1 + (KK), &Bls[B][c1 * 8]);                                    \
    }
#define COMPUTE(B)                                                             \
    {                                                                          \
        const __bf16* aF = &Als[B][(wm + fr) * 32 + fk];                       \
        const __bf16* bF = &Bls[B][(wn + fr) * 32 + fk];                       \
        bf16x8 af[4], bfr[4];                                                  \
        _Pragma("unroll") for (int mt = 0; mt < 4; ++mt)                       \
            af[mt] = *(const bf16x8*)(aF + mt * 16 * 32);                      \
        _Pragma("unroll") for (int nt = 0; nt < 4; ++nt)                       \
            bfr[nt] = *(const bf16x8*)(bF + nt * 16 * 32);                     \
        _Pragma("unroll") for (int mt = 0; mt < 4; ++mt)                       \
            _Pragma("unroll") for (int nt = 0; nt < 4; ++nt)                   \
                acc[mt][nt] = __builtin_amdgcn_mfma_f32_16x16x32_bf16(         \
                    af[mt], bfr[nt], acc[mt][nt], 0, 0, 0);                    \
    }

    STAGE(0, 0);                               // prologue: tile 0 in flight
    int cur = 0;
    for (int kk = 0; kk < E_DIM; kk += 32) {
        if (kk + 32 < E_DIM) {
            STAGE(cur ^ 1, kk + 32);           // next tile's 4 loads in flight
            asm volatile("s_waitcnt vmcnt(4)" ::: "memory");   // current 4 done
        } else {
            asm volatile("s_waitcnt vmcnt(0)" ::: "memory");   // last tile
        }
        __builtin_amdgcn_s_barrier();          // raw: no implicit vmcnt(0)
        COMPUTE(cur);                          // ds_read (lgkm-guarded) + MFMA
        __builtin_amdgcn_s_barrier();          // buf[cur^1] safe to re-stage
        cur ^= 1;
    }
#undef STAGE
#undef COMPUTE

    const int row0 = rBase + wm + (lane >> 4) * 4;
    if (cBase < 2048) {
        const float* bias;
        __bf16* Cout;
        int colBase;
        if (cBase < 1024) { bias = bq; Cout = Qb; colBase = cBase; }
        else              { bias = bv; Cout = Vb; colBase = cBase - 1024; }
        const int col0 = colBase + wn + (lane & 15);
#pragma unroll
        for (int mt = 0; mt < 4; ++mt)
#pragma unroll
            for (int nt = 0; nt < 4; ++nt) {
                int cc = col0 + nt * 16;
                float bb = bias[cc];
#pragma unroll
                for (int r = 0; r < 4; ++r)
                    Cout[(size_t)(row0 + mt * 16 + r) * E_DIM + cc] =
                        (__bf16)(acc[mt][nt][r] + bb);
            }
    } else {
        const int col0 = wn + (lane & 15);
#pragma unroll
        for (int mt = 0; mt < 4; ++mt)
#pragma unroll
            for (int nt = 0; nt < 4; ++nt) {
                int cc = col0 + nt * 16;
                if (cc < 64) {
                    float bb = bk[cc];
#pragma unroll
                    for (int r = 0; r < 4; ++r)
                        Kr[(size_t)(row0 + mt * 16 + r) * K_DIM + cc] =
                            acc[mt][nt][r] + bb;
                }
            }
    }
}

// ---------------------------------------------------------------------------
// Fused row epilogues, one block per row r = t*B + b:
//  - qn[b][t][k] = mean_h softmax_k(qb[r, h*64+k])
//  - knb[b][t][k] = LN64(kraw[r])
//  - stats[r] = {mean, rsqrt(var+eps)} of vb[r]
// ---------------------------------------------------------------------------
__global__ __launch_bounds__(256) void rowops(const __bf16* __restrict__ Qb,
                                              const float* __restrict__ Kraw,
                                              const __bf16* __restrict__ Vb,
                                              const float* __restrict__ kg,
                                              const float* __restrict__ kb,
                                              __bf16* __restrict__ QNB,
                                              __bf16* __restrict__ KNB,
                                              float2* __restrict__ ST) {
    const int r = blockIdx.x;
    const int tid = threadIdx.x;
    const int lane = tid & 63, wv = tid >> 6;
    const int t = r >> 1, b = r & 1;
    __shared__ float redq[4][64];
    __shared__ float redv[2][4];

    float acc = 0.f;
#pragma unroll
    for (int h4 = 0; h4 < 4; ++h4) {
        int h = wv * 4 + h4;
        float v = (float)Qb[(size_t)r * 1024 + h * 64 + lane];
        float m = v;
#pragma unroll
        for (int off = 32; off; off >>= 1) m = fmaxf(m, __shfl_xor(m, off));
        float e = expf(v - m);
        float ssum = e;
#pragma unroll
        for (int off = 32; off; off >>= 1) ssum += __shfl_xor(ssum, off);
        acc += e / ssum;
    }
    redq[wv][lane] = acc;

    {
        bf16x4 v4 = *(const bf16x4*)&Vb[(size_t)r * 1024 + tid * 4];
        float a = (float)v4[0], c = (float)v4[1], d = (float)v4[2], e = (float)v4[3];
        float s = a + c + d + e;
        float s2 = a * a + c * c + d * d + e * e;
#pragma unroll
        for (int off = 32; off; off >>= 1) {
            s += __shfl_xor(s, off);
            s2 += __shfl_xor(s2, off);
        }
        if (lane == 0) { redv[0][wv] = s; redv[1][wv] = s2; }
    }
    __syncthreads();

    if (tid < 64) {
        float s = redq[0][tid] + redq[1][tid] + redq[2][tid] + redq[3][tid];
        QNB[((size_t)b * T_DIM + t) * K_DIM + tid] = (__bf16)(s * (1.f / 16.f));
    } else if (tid < 128) {
        float v = Kraw[(size_t)r * K_DIM + lane];
        float s = v, s2 = v * v;
#pragma unroll
        for (int off = 32; off; off >>= 1) {
            s += __shfl_xor(s, off);
            s2 += __shfl_xor(s2, off);
        }
        float mean = s * (1.f / 64.f);
        float var = s2 * (1.f / 64.f) - mean * mean;
        float inv = rsqrtf(var + 1e-5f);
        KNB[((size_t)b * T_DIM + t) * K_DIM + lane] =
            (__bf16)((v - mean) * inv * kg[lane] + kb[lane]);
    } else if (tid == 128) {
        float s = redv[0][0] + redv[0][1] + redv[0][2] + redv[0][3];
        float s2 = redv[1][0] + redv[1][1] + redv[1][2] + redv[1][3];
        float mean = s * (1.f / 1024.f);
        float var = s2 * (1.f / 1024.f) - mean * mean;
        ST[r] = make_float2(mean, rsqrtf(var + 1e-5f));
    }
}

// ---------------------------------------------------------------------------
// r7 FUSED LN-transpose + stateU. Grid (16 c, 2 b, 16 eq) = 512 blocks = 2/CU.
// LN'd V^T tile kept LDS-resident; MFMA straight from it. VT also written
// for outPV's local-PV term.  U_c^T[e][k] = sum_{s in c} V^T[e][s]*kn[s][k].
// ---------------------------------------------------------------------------
__global__ __launch_bounds__(256) void lnT_stateU(const __bf16* __restrict__ VB,
                                                  const float2* __restrict__ ST,
                                                  const float* __restrict__ gamma,
                                                  const float* __restrict__ beta,
                                                  const __bf16* __restrict__ KNB,
                                                  __bf16* __restrict__ VT,
                                                  float* __restrict__ U) {
    __shared__ float tile[64][65];     // 16.6 KB transpose scratch
    __shared__ __bf16 knT[64 * 136];   // 17.4 KB  kn^T  [k][s]
    __shared__ __bf16 VTl[64 * 136];   // 17.4 KB  V^T   [e][t]
    const int c = blockIdx.x, b = blockIdx.y, eq = blockIdx.z;
    const int tid = threadIdx.x;
    const int lane = tid & 63;
    const int w = tid >> 6;
    const int fr = lane & 15;
    const int quad = lane >> 4;
    const int e0 = eq * 64;

    // ---- phase B: transpose kn chunk [128 s][64 k] -> knT [64 k][136] ----
    {
        int s = tid >> 1, kh = (tid & 1) * 32;
        const __bf16* src = KNB + ((size_t)b * T_DIM + c * 128 + s) * K_DIM + kh;
#pragma unroll
        for (int i8 = 0; i8 < 4; ++i8) {
            bf16x8 vv = *(const bf16x8*)&src[i8 * 8];
#pragma unroll
            for (int i = 0; i < 8; ++i) knT[(kh + i8 * 8 + i) * 136 + s] = vv[i];
        }
    }

    // ---- phase A: LN + transpose two 64t x 64e halves ----
#pragma unroll
    for (int th = 0; th < 2; ++th) {
#pragma unroll
        for (int j = 0; j < 2; ++j) {
            int idx = tid + j * 256;       // 512 chunks of 8 bf16
            int tl = idx >> 3, e8 = idx & 7;
            int r = (c * 128 + th * 64 + tl) * B_DIM + b;
            float2 st = ST[r];
            bf16x8 vv = *(const bf16x8*)&VB[(size_t)r * E_DIM + e0 + e8 * 8];
#pragma unroll
            for (int i = 0; i < 8; ++i)
                tile[tl][e8 * 8 + i] = ((float)vv[i] - st.x) * st.y;
        }
        __syncthreads();
#pragma unroll
        for (int j = 0; j < 4; ++j) {
            int idx = tid + j * 256;       // 1024 groups of 4 t
            int e = idx >> 4, t4 = idx & 15;
            float g = gamma[e0 + e], bb = beta[e0 + e];
            bf16x4 o;
#pragma unroll
            for (int i = 0; i < 4; ++i) o[i] = (__bf16)(tile[t4 * 4 + i][e] * g + bb);
            *(bf16x4*)&VT[((size_t)b * E_DIM + e0 + e) * T_DIM + c * 128 + th * 64 + t4 * 4] = o;
            *(bf16x4*)&VTl[e * 136 + th * 64 + t4 * 4] = o;
        }
        __syncthreads();                   // VTl done / tile reusable
    }

    // ---- phase C: U = VTl @ knT^T, all operands LDS-resident ----
    f32x4 acc[4] = {};
#pragma unroll
    for (int kit = 0; kit < 4; ++kit) {
        bf16x8 af = *(const bf16x8*)&VTl[(w * 16 + fr) * 136 + kit * 32 + quad * 8];
        bf16x8 bfr[4];
#pragma unroll
        for (int nt = 0; nt < 4; ++nt)
            bfr[nt] = *(const bf16x8*)&knT[(nt * 16 + fr) * 136 + kit * 32 + quad * 8];
#pragma unroll
        for (int nt = 0; nt < 4; ++nt)
            acc[nt] = __builtin_amdgcn_mfma_f32_16x16x32_bf16(
                af, bfr[nt], acc[nt], 0, 0, 0);
    }

    float* ub = U + ((size_t)(c * 2 + b) * 1024 + e0) * K_DIM;
#pragma unroll
    for (int nt = 0; nt < 4; ++nt) {
        int k = nt * 16 + fr;
#pragma unroll
        for (int r = 0; r < 4; ++r)
            ub[(size_t)(w * 16 + quad * 4 + r) * K_DIM + k] = acc[nt][r];
    }
}

// ---------------------------------------------------------------------------
// scanS: exclusive prefix over chunks; store bf16 hi + lo (residual) pair.
// Thread owns one (b,e,k); 16 sequential chunk steps.
// ---------------------------------------------------------------------------
__global__ __launch_bounds__(256) void scanS(const float* __restrict__ U,
                                             __bf16* __restrict__ Shi,
                                             __bf16* __restrict__ Slo) {
    const size_t idx = (size_t)blockIdx.x * 256 + threadIdx.x;   // 131072
    float run = 0.f;
#pragma unroll
    for (int c = 0; c < NCH; ++c) {
        __bf16 h = (__bf16)run;
        Shi[(size_t)c * 131072 + idx] = h;
        Slo[(size_t)c * 131072 + idx] = (__bf16)(run - (float)h);
        run += U[(size_t)c * 131072 + idx];
    }
}

// ---------------------------------------------------------------------------
// outPV: per chunk c, out^T[e][t] = S^T_c(hi+lo) @ qn^T  +  V^T_loc @ P^T
// where P[t][s] = qn[t]·kn[s] causal-masked within the chunk.
// Grid (16 c, 2 b, 8 eo). Block: [128 e][128 t]; 4 waves 2x2 quadrants.
// Epilogue: transpose via per-wave LDS bounce, scale rsqrt(t+1) -> OUT fp32.
// ---------------------------------------------------------------------------
__global__ __launch_bounds__(256) void outPV(const __bf16* __restrict__ QNB,
                                             const __bf16* __restrict__ KNB,
                                             const __bf16* __restrict__ VT,
                                             const __bf16* __restrict__ Shi,
                                             const __bf16* __restrict__ Slo,
                                             float* __restrict__ OUT) {
    __shared__ __align__(16) __bf16 qns[128 * 72];   // 18 KB (reused as epi scratch)
    __shared__ __align__(16) __bf16 Pl[128 * 136];   // 34.8 KB
    __shared__ __align__(16) __bf16 Vls[128 * 32];   // 8 KB
    const int c = blockIdx.x, b = blockIdx.y, eo = blockIdx.z;
    const int tid = threadIdx.x;
    const int lane = tid & 63;
    const int w = tid >> 6;
    const int fr = lane & 15;
    const int quad = lane >> 4;

    // stage qn chunk [128 t][64 k] -> qns (stride 72)
#pragma unroll
    for (int j = 0; j < 4; ++j) {
        int idx = tid + j * 256;
        int row = idx >> 3, k8 = idx & 7;
        *(bf16x8*)&qns[row * 72 + k8 * 8] =
            *(const bf16x8*)&QNB[((size_t)b * T_DIM + c * 128 + row) * K_DIM + k8 * 8];
    }
    __syncthreads();

    // ---- P^T: C[s][t] = sum_k kn[s][k] qn[t][k], causal mask, -> Pl[t][s] ----
    const __bf16* knc = KNB + ((size_t)b * T_DIM + c * 128) * K_DIM;
    {
        f32x4 pacc[8][2] = {};
#pragma unroll
        for (int kit = 0; kit < 2; ++kit) {
            bf16x8 bq[2];
#pragma unroll
            for (int nt = 0; nt < 2; ++nt) {
                int q = w * 32 + nt * 16 + fr;
                bq[nt] = *(const bf16x8*)&qns[q * 72 + kit * 32 + quad * 8];
            }
#pragma unroll
            for (int mt = 0; mt < 8; ++mt) {
                bf16x8 af = *(const bf16x8*)&knc[(size_t)(mt * 16 + fr) * K_DIM +
                                                 kit * 32 + quad * 8];
#pragma unroll
                for (int nt = 0; nt < 2; ++nt)
                    pacc[mt][nt] = __builtin_amdgcn_mfma_f32_16x16x32_bf16(
                        af, bq[nt], pacc[mt][nt], 0, 0, 0);
            }
        }
#pragma unroll
        for (int mt = 0; mt < 8; ++mt)
#pragma unroll
            for (int nt = 0; nt < 2; ++nt) {
                int q = w * 32 + nt * 16 + fr;
                int s0 = mt * 16 + quad * 4;
                bf16x4 o;
#pragma unroll
                for (int r = 0; r < 4; ++r) {
                    float val = pacc[mt][nt][r];
                    if (s0 + r > q) val = 0.f;
                    o[r] = (__bf16)val;
                }
                *(bf16x4*)&Pl[q * 136 + s0] = o;
            }
    }
    __syncthreads();

    // ---- output quadrant [64 e][64 t] per wave ----
    const int we = (w & 1) * 64, wt = (w >> 1) * 64;
    const int e0 = eo * 128;
    f32x4 acc[4][4] = {};

    if (c > 0) {   // inter-chunk: S^T(hi+lo) @ qn^T
        const __bf16* sh = Shi + (size_t)c * 131072 + ((size_t)b * 1024 + e0 + we) * K_DIM;
        const __bf16* sl = Slo + (size_t)c * 131072 + ((size_t)b * 1024 + e0 + we) * K_DIM;
#pragma unroll
        for (int kit = 0; kit < 2; ++kit) {
            bf16x8 bq[4];
#pragma unroll
            for (int nt = 0; nt < 4; ++nt) {
                int t = wt + nt * 16 + fr;
                bq[nt] = *(const bf16x8*)&qns[t * 72 + kit * 32 + quad * 8];
            }
#pragma unroll
            for (int mt = 0; mt < 4; ++mt) {
                size_t ro = (size_t)(mt * 16 + fr) * K_DIM + kit * 32 + quad * 8;
                bf16x8 ah = *(const bf16x8*)&sh[ro];
                bf16x8 al = *(const bf16x8*)&sl[ro];
#pragma unroll
                for (int nt = 0; nt < 4; ++nt) {
                    acc[mt][nt] = __builtin_amdgcn_mfma_f32_16x16x32_bf16(
                        ah, bq[nt], acc[mt][nt], 0, 0, 0);
                    acc[mt][nt] = __builtin_amdgcn_mfma_f32_16x16x32_bf16(
                        al, bq[nt], acc[mt][nt], 0, 0, 0);
                }
            }
        }
    }

    // local causal: V^T_loc @ P^T, s-contraction in 4 slices of 32
    const __bf16* vtb = VT + ((size_t)b * E_DIM + e0) * T_DIM + c * 128;
    for (int kit = 0; kit < 4; ++kit) {
        __syncthreads();
#pragma unroll
        for (int j = 0; j < 2; ++j) {
            int g = tid + j * 256;             // 512 granules
            int row = g >> 2, part = g & 3;
            GLD16(vtb + (size_t)row * T_DIM + kit * 32 + part * 8, &Vls[g * 8]);
        }
        __syncthreads();
        bf16x8 av[4], bp[4];
#pragma unroll
        for (int mt = 0; mt < 4; ++mt)
            av[mt] = *(const bf16x8*)&Vls[(we + mt * 16 + fr) * 32 + quad * 8];
#pragma unroll
        for (int nt = 0; nt < 4; ++nt)
            bp[nt] = *(const bf16x8*)&Pl[(wt + nt * 16 + fr) * 136 + kit * 32 + quad * 8];
#pragma unroll
        for (int mt = 0; mt < 4; ++mt)
#pragma unroll
            for (int nt = 0; nt < 4; ++nt)
                acc[mt][nt] = __builtin_amdgcn_mfma_f32_16x16x32_bf16(
                    av[mt], bp[nt], acc[mt][nt], 0, 0, 0);
    }
    __syncthreads();   // all compute done; reuse qns as per-wave scratch

    float* tb = (float*)qns + w * 1280;        // [64 t][20 e-slots] per wave
#pragma unroll
    for (int mt = 0; mt < 4; ++mt) {
#pragma unroll
        for (int nt = 0; nt < 4; ++nt)
            *(f32x4*)&tb[(nt * 16 + fr) * 20 + quad * 4] = acc[mt][nt];
#pragma unroll
        for (int j = 0; j < 4; ++j) {
            int fid = lane + j * 64;           // 256 float4 = 64 t x 16 e
            int trow = fid >> 2, e4 = fid & 3;
            float4 val = *(const float4*)&tb[trow * 20 + e4 * 4];
            int t = c * 128 + wt + trow;
            float sca = rsqrtf((float)(t + 1));
            float4 r = {val.x * sca, val.y * sca, val.z * sca, val.w * sca};
            *(float4*)&OUT[((size_t)t * B_DIM + b) * E_DIM + e0 + we + mt * 16 + e4 * 4] = r;
        }
    }
}

// ---------------------------------------------------------------------------
extern "C" void kernel_launch(void* const* d_in, const int* in_sizes, int n_in,
                              void* d_out, int out_size, void* d_ws,
                              size_t ws_size, hipStream_t stream) {
    const float* x = (const float*)d_in[0];
    const float* Wq = (const float*)d_in[2];
    const float* bq = (const float*)d_in[3];
    const float* Wk = (const float*)d_in[4];
    const float* bk = (const float*)d_in[5];
    const float* Wv = (const float*)d_in[6];
    const float* bv = (const float*)d_in[7];
    const float* kg = (const float*)d_in[8];
    const float* kb = (const float*)d_in[9];
    const float* vg = (const float*)d_in[10];
    const float* vb = (const float*)d_in[11];
    float* out = (float*)d_out;

    char* base = (char*)d_ws;
    const size_t MB = 1024 * 1024;
    __bf16* qb    = (__bf16*)(base + 0);         // [r][e] bf16, 8 MB
    __bf16* vbuf  = (__bf16*)(base + 8 * MB);    // [r][e] bf16, 8 MB
    float*  kraw  = (float*)(base + 16 * MB);    // [r][64] fp32, 1 MB
    __bf16* xb    = (__bf16*)(base + 17 * MB);   // 8 MB
    __bf16* wb    = (__bf16*)(base + 25 * MB);   // 4.46 MB
    __bf16* qnb   = (__bf16*)(base + 30 * MB);   // [b][t][64], 0.5 MB
    __bf16* knb   = (__bf16*)(base + 31 * MB);   // [b][t][64], 0.5 MB
    float2* stats = (float2*)(base + 32 * MB);   // 32 KB
    // aliases of dead regions:
    float*  Ubuf = (float*)(base + 0);           // 8 MB  (qb dead after rowops)
    __bf16* Shi  = (__bf16*)(base + 8 * MB);     // 4 MB  (vbuf dead after lnT_stateU)
    __bf16* Slo  = (__bf16*)(base + 12 * MB);    // 4 MB
    __bf16* vbT  = xb;                           // [b][e][t], 8 MB (xb dead after gemm)

    cvt_all<<<dim3(2048 + WROWS * 1024 / 2048), 256, 0, stream>>>(x, Wq, Wv, Wk, xb, wb);
    gemm_mfma<<<dim3(544), 256, 0, stream>>>(xb, wb, bq, bv, bk, qb, vbuf, kraw);
    rowops<<<dim3(R_DIM), 256, 0, stream>>>(qb, kraw, vbuf, kg, kb, qnb, knb, stats);
    lnT_stateU<<<dim3(NCH, 2, 16), 256, 0, stream>>>(vbuf, stats, vg, vb, knb, vbT, Ubuf);
    scanS<<<dim3(512), 256, 0, stream>>>(Ubuf, Shi, Slo);
    outPV<<<dim3(NCH, 2, 8), 256, 0, stream>>>(qnb, knb, vbT, Shi, Slo, out);
}

// Round 9
// 172.326 us; speedup vs baseline: 1.0212x; 1.0212x over previous
//
#include <hip/hip_runtime.h>
#include <math.h>

#define T_DIM 2048
#define B_DIM 2
#define E_DIM 1024
#define K_DIM 64
#define H_DIM 16
#define R_DIM (T_DIM * B_DIM)   // 4096 rows, row r = t*B + b
#define WROWS 2176              // Wq(1024) + Wv(1024) + Wk(64) + pad(64)
#define NCH 16                  // T chunks of 128 (linear-attention state)

typedef __bf16 bf16x8 __attribute__((ext_vector_type(8)));
typedef __bf16 bf16x4 __attribute__((ext_vector_type(4)));
typedef float f32x4 __attribute__((ext_vector_type(4)));

#define GLD16(gptr, lptr)                                                      \
    __builtin_amdgcn_global_load_lds(                                          \
        (const __attribute__((address_space(1))) void*)(gptr),                 \
        (__attribute__((address_space(3))) void*)(lptr), 16, 0, 0)

// ---------------------------------------------------------------------------
// Fused fp32->bf16 conversion: blocks [0,2048) convert x (4M elems);
// blocks [2048,3136) convert W-concat [Wq;Wv;Wk;pad] (2176*1024 elems).
// ---------------------------------------------------------------------------
__global__ __launch_bounds__(256) void cvt_all(const float* __restrict__ X,
                                               const float* __restrict__ Wq,
                                               const float* __restrict__ Wv,
                                               const float* __restrict__ Wk,
                                               __bf16* __restrict__ XB,
                                               __bf16* __restrict__ WB) {
    const size_t nq = (size_t)1024 * 1024;
    const size_t nk = (size_t)64 * 1024;
    bf16x8 o;
    if (blockIdx.x < 2048) {
        size_t g = ((size_t)blockIdx.x * 256 + threadIdx.x) * 8;
        float4 a = *(const float4*)&X[g];
        float4 b = *(const float4*)&X[g + 4];
        o[0] = (__bf16)a.x; o[1] = (__bf16)a.y; o[2] = (__bf16)a.z; o[3] = (__bf16)a.w;
        o[4] = (__bf16)b.x; o[5] = (__bf16)b.y; o[6] = (__bf16)b.z; o[7] = (__bf16)b.w;
        *(bf16x8*)&XB[g] = o;
    } else {
        size_t g = ((size_t)(blockIdx.x - 2048) * 256 + threadIdx.x) * 8;
        if (g < 2 * nq + nk) {
            const float* src;
            size_t off;
            if (g < nq)          { src = Wq; off = g; }
            else if (g < 2 * nq) { src = Wv; off = g - nq; }
            else                 { src = Wk; off = g - 2 * nq; }
            float4 a = *(const float4*)&src[off];
            float4 b = *(const float4*)&src[off + 4];
            o[0] = (__bf16)a.x; o[1] = (__bf16)a.y; o[2] = (__bf16)a.z; o[3] = (__bf16)a.w;
            o[4] = (__bf16)b.x; o[5] = (__bf16)b.y; o[6] = (__bf16)b.z; o[7] = (__bf16)b.w;
        } else {
#pragma unroll
            for (int i = 0; i < 8; ++i) o[i] = (__bf16)0.f;
        }
        *(bf16x8*)&WB[g] = o;
    }
}

// ---------------------------------------------------------------------------
// bf16 MFMA GEMM (r3-proven core + r7 XCD-chunked swizzle): C[4096 x 2176] =
// XB @ WB^T, 128x128 tiles, BK=32, 544 blocks (1-D). SESSION BEST (173.1us).
// Five structural variants tried and all lost to this form: explicit dbuf
// (null), BK=64+swizzle (+11us), 128x64 grid (+8us), counted-vmcnt pipeline
// (+3us). m97-idiom 2-barrier loop is the measured optimum at this geometry.
// T1 swizzle: 544 = 8 XCDs x 68; v=(bid&7)*68+(bid>>3) bijective; XCD k owns
// row-tiles [4k,4k+4) across all 17 col-tiles -> A-panels L2-resident.
// Col tiles <1024 -> Qb bf16(+bq); <2048 -> Vb bf16(+bv); else 64 -> Kr fp32.
// ---------------------------------------------------------------------------
__global__ __launch_bounds__(256) void gemm_mfma(const __bf16* __restrict__ XB,
                                                 const __bf16* __restrict__ WB,
                                                 const float* __restrict__ bq,
                                                 const float* __restrict__ bv,
                                                 const float* __restrict__ bk,
                                                 __bf16* __restrict__ Qb,
                                                 __bf16* __restrict__ Vb,
                                                 float* __restrict__ Kr) {
    __shared__ __bf16 Als[128 * 32];   // 8 KB
    __shared__ __bf16 Bls[128 * 32];   // 8 KB
    const int bid = blockIdx.x;                 // 0..543
    const int v = (bid & 7) * 68 + (bid >> 3);  // bijective XCD chunking
    const int bx = v / 17;                      // row-tile 0..31
    const int by = v % 17;                      // col-tile 0..16
    const int tid = threadIdx.x;
    const int lane = tid & 63;
    const int w = tid >> 6;
    const int wm = (w & 1) * 64;
    const int wn = (w >> 1) * 64;
    const int rBase = bx * 128;
    const int cBase = by * 128;

    const int c0 = tid, c1 = tid + 256;
    const __bf16* gA0 = XB + (size_t)(rBase + (c0 >> 2)) * E_DIM + (c0 & 3) * 8;
    const __bf16* gA1 = XB + (size_t)(rBase + (c1 >> 2)) * E_DIM + (c1 & 3) * 8;
    const __bf16* gB0 = WB + (size_t)(cBase + (c0 >> 2)) * E_DIM + (c0 & 3) * 8;
    const __bf16* gB1 = WB + (size_t)(cBase + (c1 >> 2)) * E_DIM + (c1 & 3) * 8;
    __bf16* lA0 = Als + c0 * 8;
    __bf16* lA1 = Als + c1 * 8;
    __bf16* lB0 = Bls + c0 * 8;
    __bf16* lB1 = Bls + c1 * 8;

    const int fr = lane & 15;
    const int fk = (lane >> 4) * 8;
    const __bf16* aF = Als + (wm + fr) * 32 + fk;
    const __bf16* bF = Bls + (wn + fr) * 32 + fk;

    f32x4 acc[4][4] = {};

    for (int kk = 0; kk < E_DIM; kk += 32) {
        __syncthreads();
        GLD16(gA0 + kk, lA0);
        GLD16(gA1 + kk, lA1);
        GLD16(gB0 + kk, lB0);
        GLD16(gB1 + kk, lB1);
        __syncthreads();

        bf16x8 af[4], bfr[4];
#pragma unroll
        for (int mt = 0; mt < 4; ++mt) af[mt] = *(const bf16x8*)(aF + mt * 16 * 32);
#pragma unroll
        for (int nt = 0; nt < 4; ++nt) bfr[nt] = *(const bf16x8*)(bF + nt * 16 * 32);
#pragma unroll
        for (int mt = 0; mt < 4; ++mt)
#pragma unroll
            for (int nt = 0; nt < 4; ++nt)
                acc[mt][nt] = __builtin_amdgcn_mfma_f32_16x16x32_bf16(
                    af[mt], bfr[nt], acc[mt][nt], 0, 0, 0);
    }

    const int row0 = rBase + wm + (lane >> 4) * 4;
    if (cBase < 2048) {
        const float* bias;
        __bf16* Cout;
        int colBase;
        if (cBase < 1024) { bias = bq; Cout = Qb; colBase = cBase; }
        else              { bias = bv; Cout = Vb; colBase = cBase - 1024; }
        const int col0 = colBase + wn + (lane & 15);
#pragma unroll
        for (int mt = 0; mt < 4; ++mt)
#pragma unroll
            for (int nt = 0; nt < 4; ++nt) {
                int cc = col0 + nt * 16;
                float bb = bias[cc];
#pragma unroll
                for (int r = 0; r < 4; ++r)
                    Cout[(size_t)(row0 + mt * 16 + r) * E_DIM + cc] =
                        (__bf16)(acc[mt][nt][r] + bb);
            }
    } else {
        const int col0 = wn + (lane & 15);
#pragma unroll
        for (int mt = 0; mt < 4; ++mt)
#pragma unroll
            for (int nt = 0; nt < 4; ++nt) {
                int cc = col0 + nt * 16;
                if (cc < 64) {
                    float bb = bk[cc];
#pragma unroll
                    for (int r = 0; r < 4; ++r)
                        Kr[(size_t)(row0 + mt * 16 + r) * K_DIM + cc] =
                            acc[mt][nt][r] + bb;
                }
            }
    }
}

// ---------------------------------------------------------------------------
// Fused row epilogues, one block per row r = t*B + b:
//  - qn[b][t][k] = mean_h softmax_k(qb[r, h*64+k])
//  - knb[b][t][k] = LN64(kraw[r])
//  - stats[r] = {mean, rsqrt(var+eps)} of vb[r]
// ---------------------------------------------------------------------------
__global__ __launch_bounds__(256) void rowops(const __bf16* __restrict__ Qb,
                                              const float* __restrict__ Kraw,
                                              const __bf16* __restrict__ Vb,
                                              const float* __restrict__ kg,
                                              const float* __restrict__ kb,
                                              __bf16* __restrict__ QNB,
                                              __bf16* __restrict__ KNB,
                                              float2* __restrict__ ST) {
    const int r = blockIdx.x;
    const int tid = threadIdx.x;
    const int lane = tid & 63, wv = tid >> 6;
    const int t = r >> 1, b = r & 1;
    __shared__ float redq[4][64];
    __shared__ float redv[2][4];

    float acc = 0.f;
#pragma unroll
    for (int h4 = 0; h4 < 4; ++h4) {
        int h = wv * 4 + h4;
        float v = (float)Qb[(size_t)r * 1024 + h * 64 + lane];
        float m = v;
#pragma unroll
        for (int off = 32; off; off >>= 1) m = fmaxf(m, __shfl_xor(m, off));
        float e = expf(v - m);
        float ssum = e;
#pragma unroll
        for (int off = 32; off; off >>= 1) ssum += __shfl_xor(ssum, off);
        acc += e / ssum;
    }
    redq[wv][lane] = acc;

    {
        bf16x4 v4 = *(const bf16x4*)&Vb[(size_t)r * 1024 + tid * 4];
        float a = (float)v4[0], c = (float)v4[1], d = (float)v4[2], e = (float)v4[3];
        float s = a + c + d + e;
        float s2 = a * a + c * c + d * d + e * e;
#pragma unroll
        for (int off = 32; off; off >>= 1) {
            s += __shfl_xor(s, off);
            s2 += __shfl_xor(s2, off);
        }
        if (lane == 0) { redv[0][wv] = s; redv[1][wv] = s2; }
    }
    __syncthreads();

    if (tid < 64) {
        float s = redq[0][tid] + redq[1][tid] + redq[2][tid] + redq[3][tid];
        QNB[((size_t)b * T_DIM + t) * K_DIM + tid] = (__bf16)(s * (1.f / 16.f));
    } else if (tid < 128) {
        float v = Kraw[(size_t)r * K_DIM + lane];
        float s = v, s2 = v * v;
#pragma unroll
        for (int off = 32; off; off >>= 1) {
            s += __shfl_xor(s, off);
            s2 += __shfl_xor(s2, off);
        }
        float mean = s * (1.f / 64.f);
        float var = s2 * (1.f / 64.f) - mean * mean;
        float inv = rsqrtf(var + 1e-5f);
        KNB[((size_t)b * T_DIM + t) * K_DIM + lane] =
            (__bf16)((v - mean) * inv * kg[lane] + kb[lane]);
    } else if (tid == 128) {
        float s = redv[0][0] + redv[0][1] + redv[0][2] + redv[0][3];
        float s2 = redv[1][0] + redv[1][1] + redv[1][2] + redv[1][3];
        float mean = s * (1.f / 1024.f);
        float var = s2 * (1.f / 1024.f) - mean * mean;
        ST[r] = make_float2(mean, rsqrtf(var + 1e-5f));
    }
}

// ---------------------------------------------------------------------------
// r7 FUSED LN-transpose + stateU. Grid (16 c, 2 b, 16 eq) = 512 blocks = 2/CU.
// LN'd V^T tile kept LDS-resident; MFMA straight from it. VT also written
// for outPV's local-PV term.  U_c^T[e][k] = sum_{s in c} V^T[e][s]*kn[s][k].
// LDS: tile 16.6K + knT 17.4K + VTl 17.4K = 51.4 KB. Stride-136 fragment rows
// = 2-way bank alias only (free, m136).
// ---------------------------------------------------------------------------
__global__ __launch_bounds__(256) void lnT_stateU(const __bf16* __restrict__ VB,
                                                  const float2* __restrict__ ST,
                                                  const float* __restrict__ gamma,
                                                  const float* __restrict__ beta,
                                                  const __bf16* __restrict__ KNB,
                                                  __bf16* __restrict__ VT,
                                                  float* __restrict__ U) {
    __shared__ float tile[64][65];     // 16.6 KB transpose scratch
    __shared__ __bf16 knT[64 * 136];   // 17.4 KB  kn^T  [k][s]
    __shared__ __bf16 VTl[64 * 136];   // 17.4 KB  V^T   [e][t]
    const int c = blockIdx.x, b = blockIdx.y, eq = blockIdx.z;
    const int tid = threadIdx.x;
    const int lane = tid & 63;
    const int w = tid >> 6;
    const int fr = lane & 15;
    const int quad = lane >> 4;
    const int e0 = eq * 64;

    // ---- phase B: transpose kn chunk [128 s][64 k] -> knT [64 k][136] ----
    {
        int s = tid >> 1, kh = (tid & 1) * 32;
        const __bf16* src = KNB + ((size_t)b * T_DIM + c * 128 + s) * K_DIM + kh;
#pragma unroll
        for (int i8 = 0; i8 < 4; ++i8) {
            bf16x8 vv = *(const bf16x8*)&src[i8 * 8];
#pragma unroll
            for (int i = 0; i < 8; ++i) knT[(kh + i8 * 8 + i) * 136 + s] = vv[i];
        }
    }

    // ---- phase A: LN + transpose two 64t x 64e halves ----
#pragma unroll
    for (int th = 0; th < 2; ++th) {
#pragma unroll
        for (int j = 0; j < 2; ++j) {
            int idx = tid + j * 256;       // 512 chunks of 8 bf16
            int tl = idx >> 3, e8 = idx & 7;
            int r = (c * 128 + th * 64 + tl) * B_DIM + b;
            float2 st = ST[r];
            bf16x8 vv = *(const bf16x8*)&VB[(size_t)r * E_DIM + e0 + e8 * 8];
#pragma unroll
            for (int i = 0; i < 8; ++i)
                tile[tl][e8 * 8 + i] = ((float)vv[i] - st.x) * st.y;
        }
        __syncthreads();
#pragma unroll
        for (int j = 0; j < 4; ++j) {
            int idx = tid + j * 256;       // 1024 groups of 4 t
            int e = idx >> 4, t4 = idx & 15;
            float g = gamma[e0 + e], bb = beta[e0 + e];
            bf16x4 o;
#pragma unroll
            for (int i = 0; i < 4; ++i) o[i] = (__bf16)(tile[t4 * 4 + i][e] * g + bb);
            *(bf16x4*)&VT[((size_t)b * E_DIM + e0 + e) * T_DIM + c * 128 + th * 64 + t4 * 4] = o;
            *(bf16x4*)&VTl[e * 136 + th * 64 + t4 * 4] = o;
        }
        __syncthreads();                   // VTl done / tile reusable
    }

    // ---- phase C: U = VTl @ knT^T, all operands LDS-resident ----
    f32x4 acc[4] = {};
#pragma unroll
    for (int kit = 0; kit < 4; ++kit) {
        bf16x8 af = *(const bf16x8*)&VTl[(w * 16 + fr) * 136 + kit * 32 + quad * 8];
        bf16x8 bfr[4];
#pragma unroll
        for (int nt = 0; nt < 4; ++nt)
            bfr[nt] = *(const bf16x8*)&knT[(nt * 16 + fr) * 136 + kit * 32 + quad * 8];
#pragma unroll
        for (int nt = 0; nt < 4; ++nt)
            acc[nt] = __builtin_amdgcn_mfma_f32_16x16x32_bf16(
                af, bfr[nt], acc[nt], 0, 0, 0);
    }

    float* ub = U + ((size_t)(c * 2 + b) * 1024 + e0) * K_DIM;
#pragma unroll
    for (int nt = 0; nt < 4; ++nt) {
        int k = nt * 16 + fr;
#pragma unroll
        for (int r = 0; r < 4; ++r)
            ub[(size_t)(w * 16 + quad * 4 + r) * K_DIM + k] = acc[nt][r];
    }
}

// ---------------------------------------------------------------------------
// scanS: exclusive prefix over chunks; store bf16 hi + lo (residual) pair.
// Thread owns one (b,e,k); 16 sequential chunk steps.
// ---------------------------------------------------------------------------
__global__ __launch_bounds__(256) void scanS(const float* __restrict__ U,
                                             __bf16* __restrict__ Shi,
                                             __bf16* __restrict__ Slo) {
    const size_t idx = (size_t)blockIdx.x * 256 + threadIdx.x;   // 131072
    float run = 0.f;
#pragma unroll
    for (int c = 0; c < NCH; ++c) {
        __bf16 h = (__bf16)run;
        Shi[(size_t)c * 131072 + idx] = h;
        Slo[(size_t)c * 131072 + idx] = (__bf16)(run - (float)h);
        run += U[(size_t)c * 131072 + idx];
    }
}

// ---------------------------------------------------------------------------
// outPV: per chunk c, out^T[e][t] = S^T_c(hi+lo) @ qn^T  +  V^T_loc @ P^T
// where P[t][s] = qn[t]·kn[s] causal-masked within the chunk.
// Grid (16 c, 2 b, 8 eo). Block: [128 e][128 t]; 4 waves 2x2 quadrants.
// Epilogue: transpose via per-wave LDS bounce, scale rsqrt(t+1) -> OUT fp32.
// ---------------------------------------------------------------------------
__global__ __launch_bounds__(256) void outPV(const __bf16* __restrict__ QNB,
                                             const __bf16* __restrict__ KNB,
                                             const __bf16* __restrict__ VT,
                                             const __bf16* __restrict__ Shi,
                                             const __bf16* __restrict__ Slo,
                                             float* __restrict__ OUT) {
    __shared__ __align__(16) __bf16 qns[128 * 72];   // 18 KB (reused as epi scratch)
    __shared__ __align__(16) __bf16 Pl[128 * 136];   // 34.8 KB
    __shared__ __align__(16) __bf16 Vls[128 * 32];   // 8 KB
    const int c = blockIdx.x, b = blockIdx.y, eo = blockIdx.z;
    const int tid = threadIdx.x;
    const int lane = tid & 63;
    const int w = tid >> 6;
    const int fr = lane & 15;
    const int quad = lane >> 4;

    // stage qn chunk [128 t][64 k] -> qns (stride 72)
#pragma unroll
    for (int j = 0; j < 4; ++j) {
        int idx = tid + j * 256;
        int row = idx >> 3, k8 = idx & 7;
        *(bf16x8*)&qns[row * 72 + k8 * 8] =
            *(const bf16x8*)&QNB[((size_t)b * T_DIM + c * 128 + row) * K_DIM + k8 * 8];
    }
    __syncthreads();

    // ---- P^T: C[s][t] = sum_k kn[s][k] qn[t][k], causal mask, -> Pl[t][s] ----
    const __bf16* knc = KNB + ((size_t)b * T_DIM + c * 128) * K_DIM;
    {
        f32x4 pacc[8][2] = {};
#pragma unroll
        for (int kit = 0; kit < 2; ++kit) {
            bf16x8 bq[2];
#pragma unroll
            for (int nt = 0; nt < 2; ++nt) {
                int q = w * 32 + nt * 16 + fr;
                bq[nt] = *(const bf16x8*)&qns[q * 72 + kit * 32 + quad * 8];
            }
#pragma unroll
            for (int mt = 0; mt < 8; ++mt) {
                bf16x8 af = *(const bf16x8*)&knc[(size_t)(mt * 16 + fr) * K_DIM +
                                                 kit * 32 + quad * 8];
#pragma unroll
                for (int nt = 0; nt < 2; ++nt)
                    pacc[mt][nt] = __builtin_amdgcn_mfma_f32_16x16x32_bf16(
                        af, bq[nt], pacc[mt][nt], 0, 0, 0);
            }
        }
#pragma unroll
        for (int mt = 0; mt < 8; ++mt)
#pragma unroll
            for (int nt = 0; nt < 2; ++nt) {
                int q = w * 32 + nt * 16 + fr;
                int s0 = mt * 16 + quad * 4;
                bf16x4 o;
#pragma unroll
                for (int r = 0; r < 4; ++r) {
                    float val = pacc[mt][nt][r];
                    if (s0 + r > q) val = 0.f;
                    o[r] = (__bf16)val;
                }
                *(bf16x4*)&Pl[q * 136 + s0] = o;
            }
    }
    __syncthreads();

    // ---- output quadrant [64 e][64 t] per wave ----
    const int we = (w & 1) * 64, wt = (w >> 1) * 64;
    const int e0 = eo * 128;
    f32x4 acc[4][4] = {};

    if (c > 0) {   // inter-chunk: S^T(hi+lo) @ qn^T
        const __bf16* sh = Shi + (size_t)c * 131072 + ((size_t)b * 1024 + e0 + we) * K_DIM;
        const __bf16* sl = Slo + (size_t)c * 131072 + ((size_t)b * 1024 + e0 + we) * K_DIM;
#pragma unroll
        for (int kit = 0; kit < 2; ++kit) {
            bf16x8 bq[4];
#pragma unroll
            for (int nt = 0; nt < 4; ++nt) {
                int t = wt + nt * 16 + fr;
                bq[nt] = *(const bf16x8*)&qns[t * 72 + kit * 32 + quad * 8];
            }
#pragma unroll
            for (int mt = 0; mt < 4; ++mt) {
                size_t ro = (size_t)(mt * 16 + fr) * K_DIM + kit * 32 + quad * 8;
                bf16x8 ah = *(const bf16x8*)&sh[ro];
                bf16x8 al = *(const bf16x8*)&sl[ro];
#pragma unroll
                for (int nt = 0; nt < 4; ++nt) {
                    acc[mt][nt] = __builtin_amdgcn_mfma_f32_16x16x32_bf16(
                        ah, bq[nt], acc[mt][nt], 0, 0, 0);
                    acc[mt][nt] = __builtin_amdgcn_mfma_f32_16x16x32_bf16(
                        al, bq[nt], acc[mt][nt], 0, 0, 0);
                }
            }
        }
    }

    // local causal: V^T_loc @ P^T, s-contraction in 4 slices of 32
    const __bf16* vtb = VT + ((size_t)b * E_DIM + e0) * T_DIM + c * 128;
    for (int kit = 0; kit < 4; ++kit) {
        __syncthreads();
#pragma unroll
        for (int j = 0; j < 2; ++j) {
            int g = tid + j * 256;             // 512 granules
            int row = g >> 2, part = g & 3;
            GLD16(vtb + (size_t)row * T_DIM + kit * 32 + part * 8, &Vls[g * 8]);
        }
        __syncthreads();
        bf16x8 av[4], bp[4];
#pragma unroll
        for (int mt = 0; mt < 4; ++mt)
            av[mt] = *(const bf16x8*)&Vls[(we + mt * 16 + fr) * 32 + quad * 8];
#pragma unroll
        for (int nt = 0; nt < 4; ++nt)
            bp[nt] = *(const bf16x8*)&Pl[(wt + nt * 16 + fr) * 136 + kit * 32 + quad * 8];
#pragma unroll
        for (int mt = 0; mt < 4; ++mt)
#pragma unroll
            for (int nt = 0; nt < 4; ++nt)
                acc[mt][nt] = __builtin_amdgcn_mfma_f32_16x16x32_bf16(
                    av[mt], bp[nt], acc[mt][nt], 0, 0, 0);
    }
    __syncthreads();   // all compute done; reuse qns as per-wave scratch

    float* tb = (float*)qns + w * 1280;        // [64 t][20 e-slots] per wave
#pragma unroll
    for (int mt = 0; mt < 4; ++mt) {
#pragma unroll
        for (int nt = 0; nt < 4; ++nt)
            *(f32x4*)&tb[(nt * 16 + fr) * 20 + quad * 4] = acc[mt][nt];
#pragma unroll
        for (int j = 0; j < 4; ++j) {
            int fid = lane + j * 64;           // 256 float4 = 64 t x 16 e
            int trow = fid >> 2, e4 = fid & 3;
            float4 val = *(const float4*)&tb[trow * 20 + e4 * 4];
            int t = c * 128 + wt + trow;
            float sca = rsqrtf((float)(t + 1));
            float4 r = {val.x * sca, val.y * sca, val.z * sca, val.w * sca};
            *(float4*)&OUT[((size_t)t * B_DIM + b) * E_DIM + e0 + we + mt * 16 + e4 * 4] = r;
        }
    }
}

// ---------------------------------------------------------------------------
extern "C" void kernel_launch(void* const* d_in, const int* in_sizes, int n_in,
                              void* d_out, int out_size, void* d_ws,
                              size_t ws_size, hipStream_t stream) {
    const float* x = (const float*)d_in[0];
    const float* Wq = (const float*)d_in[2];
    const float* bq = (const float*)d_in[3];
    const float* Wk = (const float*)d_in[4];
    const float* bk = (const float*)d_in[5];
    const float* Wv = (const float*)d_in[6];
    const float* bv = (const float*)d_in[7];
    const float* kg = (const float*)d_in[8];
    const float* kb = (const float*)d_in[9];
    const float* vg = (const float*)d_in[10];
    const float* vb = (const float*)d_in[11];
    float* out = (float*)d_out;

    char* base = (char*)d_ws;
    const size_t MB = 1024 * 1024;
    __bf16* qb    = (__bf16*)(base + 0);         // [r][e] bf16, 8 MB
    __bf16* vbuf  = (__bf16*)(base + 8 * MB);    // [r][e] bf16, 8 MB
    float*  kraw  = (float*)(base + 16 * MB);    // [r][64] fp32, 1 MB
    __bf16* xb    = (__bf16*)(base + 17 * MB);   // 8 MB
    __bf16* wb    = (__bf16*)(base + 25 * MB);   // 4.46 MB
    __bf16* qnb   = (__bf16*)(base + 30 * MB);   // [b][t][64], 0.5 MB
    __bf16* knb   = (__bf16*)(base + 31 * MB);   // [b][t][64], 0.5 MB
    float2* stats = (float2*)(base + 32 * MB);   // 32 KB
    // aliases of dead regions:
    float*  Ubuf = (float*)(base + 0);           // 8 MB  (qb dead after rowops)
    __bf16* Shi  = (__bf16*)(base + 8 * MB);     // 4 MB  (vbuf dead after lnT_stateU)
    __bf16* Slo  = (__bf16*)(base + 12 * MB);    // 4 MB
    __bf16* vbT  = xb;                           // [b][e][t], 8 MB (xb dead after gemm)

    cvt_all<<<dim3(2048 + WROWS * 1024 / 2048), 256, 0, stream>>>(x, Wq, Wv, Wk, xb, wb);
    gemm_mfma<<<dim3(544), 256, 0, stream>>>(xb, wb, bq, bv, bk, qb, vbuf, kraw);
    rowops<<<dim3(R_DIM), 256, 0, stream>>>(qb, kraw, vbuf, kg, kb, qnb, knb, stats);
    lnT_stateU<<<dim3(NCH, 2, 16), 256, 0, stream>>>(vbuf, stats, vg, vb, knb, vbT, Ubuf);
    scanS<<<dim3(512), 256, 0, stream>>>(Ubuf, Shi, Slo);
    outPV<<<dim3(NCH, 2, 8), 256, 0, stream>>>(qnb, knb, vbT, Shi, Slo, out);
}